// Round 1
// baseline (3848.916 us; speedup 1.0000x reference)
//
#include <hip/hip_runtime.h>
#include <math.h>
#include <algorithm>

#define Hh 14
#define Ww 14
#define LL 196
#define EMBEDD 768
#define DIMM 3072
#define DINN 6144
#define DTRR 192
#define DSTT 16
#define BATCH 2
#define ROWS (BATCH*LL)   // 392

struct IdxTab { int v[3*LL]; };

// ---------------- kernels ----------------

__global__ void im2col_kernel(const float* __restrict__ x, float* __restrict__ out){
  int i = blockIdx.x*256 + threadIdx.x;         // ROWS*768
  if (i >= ROWS*EMBEDD) return;
  int row = i / EMBEDD, col = i % EMBEDD;
  int b = row / LL, l = row % LL;
  int c = col >> 8, p = col & 255;
  int ph = p >> 4, pw = p & 15;
  int lh = l / Ww, lw = l % Ww;
  out[i] = x[ ((size_t)((b*3 + c)*224 + lh*16 + ph))*224 + lw*16 + pw ];
}

__global__ void abc_kernel(const float* __restrict__ f, const float* __restrict__ w,
                           const float* __restrict__ bias, float* __restrict__ out){
  int i = blockIdx.x*256 + threadIdx.x;   // BATCH*768
  if (i >= BATCH*EMBEDD) return;
  int b = i / EMBEDD, e = i % EMBEDD;
  float acc = bias[e];
  #pragma unroll
  for (int j=0;j<5;j++) acc += f[b*5+j]*w[e*5+j];
  out[i] = acc;
}

__global__ void gather_kernel(const float* __restrict__ xe, const float* __restrict__ pos,
                              const float* __restrict__ abc, IdxTab tab,
                              float* __restrict__ xm){
  int i = blockIdx.x*256 + threadIdx.x;   // ROWS*DIMM
  if (i >= ROWS*DIMM) return;
  int e = i % EMBEDD;
  int j = (i % DIMM) / EMBEDD;
  int row = i / DIMM;
  int b = row / LL, t = row % LL;
  int src = (j < 3) ? tab.v[j*LL + t] : t;
  xm[i] = xe[(size_t)(b*LL+src)*EMBEDD + e] + pos[src*EMBEDD+e] + abc[b*EMBEDD+e];
}

__global__ void ln_kernel(const float* __restrict__ x, const float* __restrict__ w,
                          const float* __restrict__ b, float* __restrict__ out, int D){
  int row = blockIdx.x;
  const float* xr = x + (size_t)row*D;
  float* orow = out + (size_t)row*D;
  __shared__ float red[256];
  int tid = threadIdx.x;
  float s = 0.f;
  for (int i=tid;i<D;i+=256) s += xr[i];
  red[tid]=s; __syncthreads();
  for (int off=128;off>0;off>>=1){ if(tid<off) red[tid]+=red[tid+off]; __syncthreads(); }
  float mean = red[0]/(float)D;
  __syncthreads();
  float v=0.f;
  for (int i=tid;i<D;i+=256){ float d=xr[i]-mean; v+=d*d; }
  red[tid]=v; __syncthreads();
  for (int off=128;off>0;off>>=1){ if(tid<off) red[tid]+=red[tid+off]; __syncthreads(); }
  float inv = 1.0f/sqrtf(red[0]/(float)D + 1e-5f);
  for (int i=tid;i<D;i+=256) orow[i] = (xr[i]-mean)*inv*w[i] + b[i];
}

// C[M,N] = A[M,K] @ W[N,K]^T  (+bias)  MODE: 0=store, 1=softplus(store), 2=C+=
template<int MODE>
__launch_bounds__(256)
__global__ void gemm_f32(const float* __restrict__ A, int lda,
                         const float* __restrict__ W,
                         const float* __restrict__ bias,
                         float* __restrict__ C, int ldc,
                         int M, int N, int K){
  __shared__ __align__(16) float As[16][64];
  __shared__ __align__(16) float Bs[16][64];
  int tid = threadIdx.x;
  int tx = tid & 15, ty = tid >> 4;
  int arow = tid >> 2;
  int acol = (tid & 3) << 2;
  int gm = blockIdx.y*64 + arow;
  int gn = blockIdx.x*64 + arow;
  float acc[4][4] = {};
  for (int k0=0;k0<K;k0+=16){
    float4 av = make_float4(0.f,0.f,0.f,0.f);
    float4 bv = make_float4(0.f,0.f,0.f,0.f);
    if (gm < M) av = *(const float4*)(A + (size_t)gm*lda + k0 + acol);
    if (gn < N) bv = *(const float4*)(W + (size_t)gn*K + k0 + acol);
    As[acol+0][arow]=av.x; As[acol+1][arow]=av.y; As[acol+2][arow]=av.z; As[acol+3][arow]=av.w;
    Bs[acol+0][arow]=bv.x; Bs[acol+1][arow]=bv.y; Bs[acol+2][arow]=bv.z; Bs[acol+3][arow]=bv.w;
    __syncthreads();
    #pragma unroll
    for (int k=0;k<16;k++){
      float4 a4 = *(const float4*)&As[k][ty<<2];
      float4 b4 = *(const float4*)&Bs[k][tx<<2];
      float aa[4]={a4.x,a4.y,a4.z,a4.w};
      float bb[4]={b4.x,b4.y,b4.z,b4.w};
      #pragma unroll
      for (int i2=0;i2<4;i2++)
        #pragma unroll
        for (int j2=0;j2<4;j2++)
          acc[i2][j2] += aa[i2]*bb[j2];
    }
    __syncthreads();
  }
  #pragma unroll
  for (int i2=0;i2<4;i2++){
    int r = blockIdx.y*64 + (ty<<2) + i2;
    if (r >= M) continue;
    #pragma unroll
    for (int j2=0;j2<4;j2++){
      int c = blockIdx.x*64 + (tx<<2) + j2;
      if (c >= N) continue;
      float v = acc[i2][j2];
      if (bias) v += bias[c];
      if (MODE==1) v = (v > 0.f) ? v + log1pf(expf(-v)) : log1pf(expf(v));
      if (MODE==2) C[(size_t)r*ldc+c] += v;
      else         C[(size_t)r*ldc+c]  = v;
    }
  }
}

__global__ void conv_silu_kernel(const float* __restrict__ xr, const float* __restrict__ w,
                                 const float* __restrict__ bias, float* __restrict__ out){
  int i = blockIdx.x*256 + threadIdx.x;   // ROWS*DINN
  if (i >= ROWS*DINN) return;
  int c = i % DINN;
  int row = i / DINN;
  int b = row / LL, t = row % LL;
  float acc = bias[c];
  #pragma unroll
  for (int k=0;k<4;k++){
    int tt = t - 3 + k;
    if (tt >= 0) acc += xr[(size_t)(b*LL+tt)*(2*DINN) + c] * w[c*4+k];
  }
  out[i] = acc / (1.f + expf(-acc));   // silu
}

__global__ void scan_kernel(const float* __restrict__ dt, const float* __restrict__ dblp,
                            const float* __restrict__ xs, const float* __restrict__ xr,
                            const float* __restrict__ A_log, const float* __restrict__ Dp,
                            float* __restrict__ y){
  int d = blockIdx.x*256 + threadIdx.x;  // 0..DINN-1
  int b = blockIdx.y;
  float A[16], st[16];
  #pragma unroll
  for (int n=0;n<16;n++){ A[n] = -expf(A_log[d*16+n]); st[n]=0.f; }
  float Dd = Dp[d];
  for (int t=0;t<LL;t++){
    size_t row = (size_t)(b*LL + t);
    float dtv = dt[row*DINN + d];
    float xv  = xs[row*DINN + d];
    float resv= xr[row*(2*DINN) + DINN + d];
    const float* bc = dblp + row*224 + 192;
    float dtx = dtv*xv;
    float acc = 0.f;
    #pragma unroll
    for (int n=0;n<16;n++){
      st[n] = st[n]*expf(dtv*A[n]) + dtx*bc[n];
      acc += st[n]*bc[16+n];
    }
    float yv = acc + xv*Dd;
    y[row*DINN + d] = yv * (resv/(1.f + expf(-resv)));
  }
}

__global__ void mean_kernel(const float* __restrict__ xp, float* __restrict__ out){
  int i = blockIdx.x*256 + threadIdx.x; // BATCH*768
  if (i >= BATCH*EMBEDD) return;
  int b = i/EMBEDD, e = i%EMBEDD;
  float s = 0.f;
  for (int t=0;t<LL;t++) s += xp[(size_t)(b*LL+t)*EMBEDD + e];
  out[i] = s / 196.0f;
}

// ---------------- host: exact numpy index replication ----------------

static void build_tables(int* tab){
  const double TWO_PI = 6.283185307179586;
  { // spiral
    int order[512]; int cnt=0;
    for (int r=0;r<14;r++){
      int m = (2*r > 8) ? 2*r : 8;
      double step = TWO_PI/(double)m;
      for (int a=0;a<m;a++){
        double ang = (double)a*step;
        double hv = 7.0 + (double)r*cos(ang);
        double wv = 7.0 + (double)r*sin(ang);
        int h=(int)hv, w=(int)wv;   // trunc toward zero, same as Python int()
        if (h>=0&&h<14&&w>=0&&w<14) order[cnt++] = h*14+w;
      }
    }
    bool seen[LL]={};
    int n=0;
    for (int i=0;i<cnt;i++){ int v=order[i]; if(!seen[v]){seen[v]=true; tab[n++]=v;} }
    for (int v=0;v<LL;v++) if(!seen[v]) tab[n++]=v;
  }
  { // radial: sort by (-d, a), stable
    static double dd[LL], aa[LL];
    static int id[LL];
    for (int h=0;h<14;h++) for (int w=0;w<14;w++){
      int i=h*14+w;
      double dh=h-7, dw=w-7;
      dd[i]=sqrt(dh*dh+dw*dw); aa[i]=atan2(dh,dw); id[i]=i;
    }
    std::stable_sort(id, id+LL, [](int x,int y){
      if (dd[x]!=dd[y]) return dd[x]>dd[y];
      return aa[x]<aa[y];
    });
    for (int i=0;i<LL;i++) tab[LL+i]=id[i];
  }
  { // boundary
    int n=0;
    for (int h=0;h<14;h++) for (int w=0;w<14;w++){ int i=h*14+w; if(h==0||h==13||w==0||w==13) tab[2*LL+n++]=i; }
    for (int h=0;h<14;h++) for (int w=0;w<14;w++){ int i=h*14+w; if(!(h==0||h==13||w==0||w==13)) tab[2*LL+n++]=i; }
  }
}

extern "C" void kernel_launch(void* const* d_in, const int* in_sizes, int n_in,
                              void* d_out, int out_size, void* d_ws, size_t ws_size,
                              hipStream_t stream){
  const float* x        = (const float*)d_in[0];
  const float* abcde_f  = (const float*)d_in[1];
  const float* patch_w  = (const float*)d_in[2];
  const float* patch_b  = (const float*)d_in[3];
  const float* pos      = (const float*)d_in[4];
  const float* abcde_w  = (const float*)d_in[5];
  const float* abcde_b  = (const float*)d_in[6];
  const float* ln_w     = (const float*)d_in[7];
  const float* ln_b     = (const float*)d_in[8];
  const float* in_proj  = (const float*)d_in[9];
  const float* conv_w   = (const float*)d_in[10];
  const float* conv_b   = (const float*)d_in[11];
  const float* x_proj   = (const float*)d_in[12];
  const float* dt_proj  = (const float*)d_in[13];

  // setup_inputs() dict order puts dt_proj_b LAST (index 21); detect defensively.
  int iA=14, iD=15, iO=16, iPW=17, iPB=18, iNW=19, iNB=20, iDTB=21;
  if (n_in > 14 && in_sizes[14] == 2*DINN && in_sizes[15] == 2*DINN*DSTT) {
    // signature order fallback: dt_proj_b at 14
    iDTB=14; iA=15; iD=16; iO=17; iPW=18; iPB=19; iNW=20; iNB=21;
  }
  const float* A_log    = (const float*)d_in[iA];
  const float* D_param  = (const float*)d_in[iD];
  const float* out_proj = (const float*)d_in[iO];
  const float* proj_w   = (const float*)d_in[iPW];
  const float* proj_b   = (const float*)d_in[iPB];
  const float* norm_w   = (const float*)d_in[iNW];
  const float* norm_b   = (const float*)d_in[iNB];
  const float* dt_b     = (const float*)d_in[iDTB];

  static IdxTab tab;
  build_tables(tab.v);   // deterministic, identical every call

  char* ws = (char*)d_ws;
  size_t off = 0;
  auto alloc = [&](size_t bytes)->void* { void* p = ws + off; off = (off + bytes + 255) & ~(size_t)255; return p; };
  float* Aim   = (float*)alloc((size_t)ROWS*EMBEDD*4);
  float* xe0   = (float*)alloc((size_t)ROWS*EMBEDD*4);
  float* abc   = (float*)alloc((size_t)BATCH*EMBEDD*4);
  float* xm    = (float*)alloc((size_t)ROWS*DIMM*4);
  float* xln   = (float*)alloc((size_t)ROWS*DIMM*4);
  float* xrb   = (float*)alloc((size_t)ROWS*2*DINN*4);
  float* xsc   = (float*)alloc((size_t)ROWS*DINN*4);
  float* dblb  = (float*)alloc((size_t)ROWS*224*4);
  float* dtb   = (float*)alloc((size_t)ROWS*DINN*4);
  float* ybuf  = (float*)alloc((size_t)ROWS*DINN*4);
  float* xp    = (float*)alloc((size_t)ROWS*EMBEDD*4);
  (void)ws_size; (void)out_size;

  im2col_kernel<<<(ROWS*EMBEDD+255)/256,256,0,stream>>>(x, Aim);
  abc_kernel<<<(BATCH*EMBEDD+255)/256,256,0,stream>>>(abcde_f, abcde_w, abcde_b, abc);
  {
    dim3 g((EMBEDD+63)/64,(ROWS+63)/64);
    gemm_f32<0><<<g,256,0,stream>>>(Aim, EMBEDD, patch_w, patch_b, xe0, EMBEDD, ROWS, EMBEDD, EMBEDD);
  }
  gather_kernel<<<(ROWS*DIMM+255)/256,256,0,stream>>>(xe0, pos, abc, tab, xm);

  for (int l=0;l<2;l++){
    ln_kernel<<<ROWS,256,0,stream>>>(xm, ln_w + l*DIMM, ln_b + l*DIMM, xln, DIMM);
    {
      dim3 g((2*DINN+63)/64,(ROWS+63)/64);
      gemm_f32<0><<<g,256,0,stream>>>(xln, DIMM, in_proj + (size_t)l*2*DINN*DIMM, nullptr, xrb, 2*DINN, ROWS, 2*DINN, DIMM);
    }
    conv_silu_kernel<<<(ROWS*DINN+255)/256,256,0,stream>>>(xrb, conv_w + (size_t)l*DINN*4, conv_b + l*DINN, xsc);
    {
      dim3 g((224+63)/64,(ROWS+63)/64);
      gemm_f32<0><<<g,256,0,stream>>>(xsc, DINN, x_proj + (size_t)l*224*DINN, nullptr, dblb, 224, ROWS, 224, DINN);
    }
    {
      dim3 g((DINN+63)/64,(ROWS+63)/64);
      gemm_f32<1><<<g,256,0,stream>>>(dblb, 224, dt_proj + (size_t)l*DINN*DTRR, dt_b + l*DINN, dtb, DINN, ROWS, DINN, DTRR);
    }
    scan_kernel<<<dim3(DINN/256, BATCH),256,0,stream>>>(dtb, dblb, xsc, xrb,
                     A_log + (size_t)l*DINN*DSTT, D_param + l*DINN, ybuf);
    {
      dim3 g((DIMM+63)/64,(ROWS+63)/64);
      gemm_f32<2><<<g,256,0,stream>>>(ybuf, DINN, out_proj + (size_t)l*DIMM*DINN, nullptr, xm, DIMM, ROWS, DIMM, DINN);
    }
  }
  {
    dim3 g((EMBEDD+63)/64,(ROWS+63)/64);
    gemm_f32<0><<<g,256,0,stream>>>(xm, DIMM, proj_w, proj_b, xp, EMBEDD, ROWS, EMBEDD, DIMM);
  }
  ln_kernel<<<ROWS,256,0,stream>>>(xp, norm_w, norm_b, xp, EMBEDD);
  mean_kernel<<<(BATCH*EMBEDD+255)/256,256,0,stream>>>(xp, (float*)d_out);
}

// Round 2
// 1896.409 us; speedup vs baseline: 2.0296x; 2.0296x over previous
//
#include <hip/hip_runtime.h>
#include <math.h>
#include <algorithm>

#define Hh 14
#define Ww 14
#define LL 196
#define EMBEDD 768
#define DIMM 3072
#define DINN 6144
#define DTRR 192
#define DSTT 16
#define BATCH 2
#define ROWS (BATCH*LL)   // 392
#define MPAD 512          // rows padded to multiple of 128

typedef __attribute__((ext_vector_type(8))) short short8;
typedef __attribute__((ext_vector_type(4))) float floatx4;

struct IdxTab { int v[3*LL]; };

__device__ __forceinline__ unsigned short f2bf(float f){
  union { float f; unsigned u; } v; v.f = f;
  unsigned r = v.u + 0x7fff + ((v.u >> 16) & 1);   // RNE
  return (unsigned short)(r >> 16);
}

// ---------------- elementwise / small kernels ----------------

__global__ void im2col_kernel(const float* __restrict__ x, unsigned short* __restrict__ out){
  int i = blockIdx.x*256 + threadIdx.x;         // ROWS*768
  if (i >= ROWS*EMBEDD) return;
  int row = i / EMBEDD, col = i % EMBEDD;
  int b = row / LL, l = row % LL;
  int c = col >> 8, p = col & 255;
  int ph = p >> 4, pw = p & 15;
  int lh = l / Ww, lw = l % Ww;
  out[i] = f2bf(x[ ((size_t)((b*3 + c)*224 + lh*16 + ph))*224 + lw*16 + pw ]);
}

__global__ void abc_kernel(const float* __restrict__ f, const float* __restrict__ w,
                           const float* __restrict__ bias, float* __restrict__ out){
  int i = blockIdx.x*256 + threadIdx.x;   // BATCH*768
  if (i >= BATCH*EMBEDD) return;
  int b = i / EMBEDD, e = i % EMBEDD;
  float acc = bias[e];
  #pragma unroll
  for (int j=0;j<5;j++) acc += f[b*5+j]*w[e*5+j];
  out[i] = acc;
}

__global__ void gather_kernel(const float* __restrict__ xe, const float* __restrict__ pos,
                              const float* __restrict__ abc, IdxTab tab,
                              float* __restrict__ xm){
  int i = blockIdx.x*256 + threadIdx.x;   // ROWS*DIMM
  if (i >= ROWS*DIMM) return;
  int e = i % EMBEDD;
  int j = (i % DIMM) / EMBEDD;
  int row = i / DIMM;
  int b = row / LL, t = row % LL;
  int src = (j < 3) ? tab.v[j*LL + t] : t;
  xm[i] = xe[(size_t)(b*LL+src)*EMBEDD + e] + pos[src*EMBEDD+e] + abc[b*EMBEDD+e];
}

// BF16OUT=1: write ushort bf16, else float
template<int BF16OUT>
__global__ void ln_kernel(const float* __restrict__ x, const float* __restrict__ w,
                          const float* __restrict__ b, void* __restrict__ outp, int D){
  int row = blockIdx.x;
  const float* xr = x + (size_t)row*D;
  __shared__ float red[256];
  int tid = threadIdx.x;
  float s = 0.f;
  for (int i=tid;i<D;i+=256) s += xr[i];
  red[tid]=s; __syncthreads();
  for (int off=128;off>0;off>>=1){ if(tid<off) red[tid]+=red[tid+off]; __syncthreads(); }
  float mean = red[0]/(float)D;
  __syncthreads();
  float v=0.f;
  for (int i=tid;i<D;i+=256){ float d=xr[i]-mean; v+=d*d; }
  red[tid]=v; __syncthreads();
  for (int off=128;off>0;off>>=1){ if(tid<off) red[tid]+=red[tid+off]; __syncthreads(); }
  float inv = 1.0f/sqrtf(red[0]/(float)D + 1e-5f);
  for (int i=tid;i<D;i+=256){
    float o = (xr[i]-mean)*inv*w[i] + b[i];
    if (BF16OUT) ((unsigned short*)outp)[(size_t)row*D + i] = f2bf(o);
    else         ((float*)outp)[(size_t)row*D + i] = o;
  }
}

__global__ void zero_kernel(float* __restrict__ p, int n){
  int i = blockIdx.x*256 + threadIdx.x;
  if (i < n) p[i] = 0.f;
}

__global__ void cvt_dtin_kernel(const float* __restrict__ dblb, unsigned short* __restrict__ dtin){
  int i = blockIdx.x*256 + threadIdx.x;   // ROWS*192
  if (i >= ROWS*DTRR) return;
  int row = i / DTRR, col = i % DTRR;
  dtin[(size_t)row*DTRR + col] = f2bf(dblb[(size_t)row*224 + col]);
}

__global__ void cvt_bf16_kernel(const float* __restrict__ src, unsigned short* __restrict__ dst, int n){
  int i = blockIdx.x*256 + threadIdx.x;
  if (i < n) dst[i] = f2bf(src[i]);
}

// ---------------- bf16 MFMA GEMM ----------------
// C[M,N](fp32) = A[M,K](bf16, rows padded >= m0+128) @ W[N,K](fp32)^T
// MODE: 0 = store (+bias), 1 = softplus(v+bias) store, 2 = C += v, 3 = atomicAdd
// Split-K via blockIdx.z with slice length ksl.
template<int MODE>
__launch_bounds__(256)
__global__ void gemm_bf16(const unsigned short* __restrict__ A, int lda,
                          const float* __restrict__ Wf,
                          const float* __restrict__ bias,
                          float* __restrict__ C, int ldc,
                          int M, int N, int K, int ksl){
  __shared__ short As[128*32];
  __shared__ short Bs[128*32];
  int tid = threadIdx.x;
  int wave = tid >> 6, lane = tid & 63;
  int m0 = blockIdx.y*128, n0 = blockIdx.x*128;
  int wm = (wave&1)*64, wn = (wave>>1)*64;
  int k_beg = blockIdx.z * ksl;
  int k_end = k_beg + ksl; if (k_end > K) k_end = K;

  floatx4 acc[4][4] = {};

  for (int k0 = k_beg; k0 < k_end; k0 += 32){
    // --- stage A tile (bf16) via global_load_lds, 2 x 16B per thread ---
    #pragma unroll
    for (int q=0;q<2;q++){
      int li = q*256 + tid;                       // 0..511 slots of 8 bf16
      const unsigned short* src = A + (size_t)(m0 + (li>>2))*lda + k0 + (li&3)*8;
      __builtin_amdgcn_global_load_lds(
          (const __attribute__((address_space(1))) void*)src,
          (__attribute__((address_space(3))) void*)(As + li*8), 16, 0, 0);
    }
    // --- stage B tile: fp32 -> bf16 convert in registers, ds_write_b128 ---
    #pragma unroll
    for (int q=0;q<2;q++){
      int li = q*256 + tid;
      int bn = n0 + (li>>2); if (bn >= N) bn = N-1;    // clamp: garbage cols guarded at store
      const float* src = Wf + (size_t)bn*K + k0 + (li&3)*8;
      float4 f0 = *(const float4*)(src);
      float4 f1 = *(const float4*)(src+4);
      union { short8 v; unsigned short u[8]; } pk;
      pk.u[0]=f2bf(f0.x); pk.u[1]=f2bf(f0.y); pk.u[2]=f2bf(f0.z); pk.u[3]=f2bf(f0.w);
      pk.u[4]=f2bf(f1.x); pk.u[5]=f2bf(f1.y); pk.u[6]=f2bf(f1.z); pk.u[7]=f2bf(f1.w);
      *(short8*)(Bs + li*8) = pk.v;
    }
    __syncthreads();
    // --- fragments + MFMA ---
    int rsel = lane & 15, ksel = lane >> 4;   // ksel in 0..3 -> k offset ksel*8
    short8 afr[4], bfr[4];
    #pragma unroll
    for (int i=0;i<4;i++) afr[i] = *(const short8*)(As + (wm + i*16 + rsel)*32 + ksel*8);
    #pragma unroll
    for (int j=0;j<4;j++) bfr[j] = *(const short8*)(Bs + (wn + j*16 + rsel)*32 + ksel*8);
    #pragma unroll
    for (int i=0;i<4;i++)
      #pragma unroll
      for (int j=0;j<4;j++)
        acc[i][j] = __builtin_amdgcn_mfma_f32_16x16x32_bf16(afr[i], bfr[j], acc[i][j], 0,0,0);
    __syncthreads();
  }

  // --- epilogue: D[m][n]: m = quad*4 + reg, n = lane&15 ---
  int col = lane & 15, quad = lane >> 4;
  #pragma unroll
  for (int i=0;i<4;i++){
    #pragma unroll
    for (int j=0;j<4;j++){
      int gc = n0 + wn + j*16 + col;
      if (gc >= N) continue;
      #pragma unroll
      for (int r=0;r<4;r++){
        int gr = m0 + wm + i*16 + quad*4 + r;
        if (gr >= M) continue;
        float v = acc[i][j][r];
        if (MODE==0){
          if (bias) v += bias[gc];
          C[(size_t)gr*ldc + gc] = v;
        } else if (MODE==1){
          v += bias[gc];
          float sp = fmaxf(v, 0.f) + log1pf(expf(-fabsf(v)));
          C[(size_t)gr*ldc + gc] = sp;
        } else if (MODE==2){
          C[(size_t)gr*ldc + gc] += v;
        } else {
          atomicAdd(&C[(size_t)gr*ldc + gc], v);
        }
      }
    }
  }
}

// ---------------- conv + silu ----------------
__global__ void conv_silu_kernel(const float* __restrict__ xr, const float* __restrict__ w,
                                 const float* __restrict__ bias, float* __restrict__ out,
                                 unsigned short* __restrict__ out_bf){
  int i = blockIdx.x*256 + threadIdx.x;   // ROWS*DINN
  if (i >= ROWS*DINN) return;
  int c = i % DINN;
  int row = i / DINN;
  int b = row / LL, t = row % LL;
  float acc = bias[c];
  #pragma unroll
  for (int k=0;k<4;k++){
    int tt = t - 3 + k;
    if (tt >= 0) acc += xr[(size_t)(b*LL+tt)*(2*DINN) + c] * w[c*4+k];
  }
  float s = acc / (1.f + expf(-acc));
  out[i] = s;
  out_bf[i] = f2bf(s);
}

// ---------------- selective scan ----------------
__global__ void scan_kernel(const float* __restrict__ dt, const float* __restrict__ dblp,
                            const float* __restrict__ xs, const float* __restrict__ xr,
                            const float* __restrict__ A_log, const float* __restrict__ Dp,
                            unsigned short* __restrict__ y){
  int d = blockIdx.x*64 + threadIdx.x;  // 0..DINN-1
  int b = blockIdx.y;
  float A[16], st[16];
  #pragma unroll
  for (int n=0;n<16;n++){ A[n] = -expf(A_log[d*16+n]); st[n]=0.f; }
  float Dd = Dp[d];
  for (int t=0;t<LL;t++){
    size_t row = (size_t)(b*LL + t);
    float dtv = dt[row*DINN + d];
    float xv  = xs[row*DINN + d];
    float resv= xr[row*(2*DINN) + DINN + d];
    const float* bc = dblp + row*224 + 192;
    float dtx = dtv*xv;
    float acc = 0.f;
    #pragma unroll
    for (int n=0;n<16;n++){
      st[n] = st[n]*expf(dtv*A[n]) + dtx*bc[n];
      acc += st[n]*bc[16+n];
    }
    float yv = acc + xv*Dd;
    y[row*DINN + d] = f2bf(yv * (resv/(1.f + expf(-resv))));
  }
}

__global__ void mean_kernel(const float* __restrict__ xp, float* __restrict__ out){
  int i = blockIdx.x*256 + threadIdx.x; // BATCH*768
  if (i >= BATCH*EMBEDD) return;
  int b = i/EMBEDD, e = i%EMBEDD;
  float s = 0.f;
  for (int t=0;t<LL;t++) s += xp[(size_t)(b*LL+t)*EMBEDD + e];
  out[i] = s / 196.0f;
}

// ---------------- host: exact numpy index replication ----------------

static void build_tables(int* tab){
  const double TWO_PI = 6.283185307179586;
  { // spiral
    int order[512]; int cnt=0;
    for (int r=0;r<14;r++){
      int m = (2*r > 8) ? 2*r : 8;
      double step = TWO_PI/(double)m;
      for (int a=0;a<m;a++){
        double ang = (double)a*step;
        double hv = 7.0 + (double)r*cos(ang);
        double wv = 7.0 + (double)r*sin(ang);
        int h=(int)hv, w=(int)wv;
        if (h>=0&&h<14&&w>=0&&w<14) order[cnt++] = h*14+w;
      }
    }
    bool seen[LL]={};
    int n=0;
    for (int i=0;i<cnt;i++){ int v=order[i]; if(!seen[v]){seen[v]=true; tab[n++]=v;} }
    for (int v=0;v<LL;v++) if(!seen[v]) tab[n++]=v;
  }
  { // radial
    static double dd[LL], aa[LL];
    static int id[LL];
    for (int h=0;h<14;h++) for (int w=0;w<14;w++){
      int i=h*14+w;
      double dh=h-7, dw=w-7;
      dd[i]=sqrt(dh*dh+dw*dw); aa[i]=atan2(dh,dw); id[i]=i;
    }
    std::stable_sort(id, id+LL, [](int x,int y){
      if (dd[x]!=dd[y]) return dd[x]>dd[y];
      return aa[x]<aa[y];
    });
    for (int i=0;i<LL;i++) tab[LL+i]=id[i];
  }
  { // boundary
    int n=0;
    for (int h=0;h<14;h++) for (int w=0;w<14;w++){ int i=h*14+w; if(h==0||h==13||w==0||w==13) tab[2*LL+n++]=i; }
    for (int h=0;h<14;h++) for (int w=0;w<14;w++){ int i=h*14+w; if(!(h==0||h==13||w==0||w==13)) tab[2*LL+n++]=i; }
  }
}

extern "C" void kernel_launch(void* const* d_in, const int* in_sizes, int n_in,
                              void* d_out, int out_size, void* d_ws, size_t ws_size,
                              hipStream_t stream){
  const float* x        = (const float*)d_in[0];
  const float* abcde_f  = (const float*)d_in[1];
  const float* patch_w  = (const float*)d_in[2];
  const float* patch_b  = (const float*)d_in[3];
  const float* pos      = (const float*)d_in[4];
  const float* abcde_w  = (const float*)d_in[5];
  const float* abcde_b  = (const float*)d_in[6];
  const float* ln_w     = (const float*)d_in[7];
  const float* ln_b     = (const float*)d_in[8];
  const float* in_proj  = (const float*)d_in[9];
  const float* conv_w   = (const float*)d_in[10];
  const float* conv_b   = (const float*)d_in[11];
  const float* x_proj   = (const float*)d_in[12];
  const float* dt_proj  = (const float*)d_in[13];

  int iA=14, iD=15, iO=16, iPW=17, iPB=18, iNW=19, iNB=20, iDTB=21;
  if (n_in > 14 && in_sizes[14] == 2*DINN && in_sizes[15] == 2*DINN*DSTT) {
    iDTB=14; iA=15; iD=16; iO=17; iPW=18; iPB=19; iNW=20; iNB=21;
  }
  const float* A_log    = (const float*)d_in[iA];
  const float* D_param  = (const float*)d_in[iD];
  const float* out_proj = (const float*)d_in[iO];
  const float* proj_w   = (const float*)d_in[iPW];
  const float* proj_b   = (const float*)d_in[iPB];
  const float* norm_w   = (const float*)d_in[iNW];
  const float* norm_b   = (const float*)d_in[iNB];
  const float* dt_b     = (const float*)d_in[iDTB];

  static IdxTab tab;
  build_tables(tab.v);

  char* ws = (char*)d_ws;
  size_t off = 0;
  auto alloc = [&](size_t bytes)->void* { void* p = ws + off; off = (off + bytes + 255) & ~(size_t)255; return p; };
  unsigned short* Aim_bf  = (unsigned short*)alloc((size_t)MPAD*EMBEDD*2);
  float*          xe0     = (float*)alloc((size_t)ROWS*EMBEDD*4);
  float*          abc     = (float*)alloc((size_t)BATCH*EMBEDD*4);
  float*          xm      = (float*)alloc((size_t)ROWS*DIMM*4);
  unsigned short* xln_bf  = (unsigned short*)alloc((size_t)MPAD*DIMM*2);
  float*          xrb     = (float*)alloc((size_t)ROWS*2*DINN*4);
  float*          xsc     = (float*)alloc((size_t)ROWS*DINN*4);
  unsigned short* xsc_bf  = (unsigned short*)alloc((size_t)MPAD*DINN*2);
  float*          dblb    = (float*)alloc((size_t)MPAD*224*4);
  unsigned short* dtin_bf = (unsigned short*)alloc((size_t)MPAD*DTRR*2);
  float*          dtb     = (float*)alloc((size_t)ROWS*DINN*4);
  unsigned short* y_bf    = (unsigned short*)alloc((size_t)MPAD*DINN*2);
  unsigned short* xm_bf   = (unsigned short*)alloc((size_t)MPAD*DIMM*2);
  float*          xp      = (float*)alloc((size_t)ROWS*EMBEDD*4);
  (void)ws_size; (void)out_size; (void)n_in;

  // ---- patch embed ----
  im2col_kernel<<<(ROWS*EMBEDD+255)/256,256,0,stream>>>(x, Aim_bf);
  abc_kernel<<<(BATCH*EMBEDD+255)/256,256,0,stream>>>(abcde_f, abcde_w, abcde_b, abc);
  gemm_bf16<0><<<dim3(6,4),256,0,stream>>>(Aim_bf, EMBEDD, patch_w, patch_b, xe0, EMBEDD,
                                           ROWS, EMBEDD, EMBEDD, EMBEDD);
  gather_kernel<<<(ROWS*DIMM+255)/256,256,0,stream>>>(xe0, pos, abc, tab, xm);

  for (int l=0;l<2;l++){
    ln_kernel<1><<<ROWS,256,0,stream>>>(xm, ln_w + l*DIMM, ln_b + l*DIMM, xln_bf, DIMM);
    // in_proj: M=392 N=12288 K=3072
    gemm_bf16<0><<<dim3(96,4),256,0,stream>>>(xln_bf, DIMM, in_proj + (size_t)l*2*DINN*DIMM,
                                              nullptr, xrb, 2*DINN, ROWS, 2*DINN, DIMM, DIMM);
    conv_silu_kernel<<<(ROWS*DINN+255)/256,256,0,stream>>>(xrb, conv_w + (size_t)l*DINN*4,
                                                           conv_b + l*DINN, xsc, xsc_bf);
    // x_proj: M=392 N=224 K=6144, split-K=8 via atomicAdd
    zero_kernel<<<(MPAD*224+255)/256,256,0,stream>>>(dblb, MPAD*224);
    gemm_bf16<3><<<dim3(2,4,8),256,0,stream>>>(xsc_bf, DINN, x_proj + (size_t)l*224*DINN,
                                               nullptr, dblb, 224, ROWS, 224, DINN, DINN/8);
    cvt_dtin_kernel<<<(ROWS*DTRR+255)/256,256,0,stream>>>(dblb, dtin_bf);
    // dt_proj: M=392 N=6144 K=192, softplus(+bias)
    gemm_bf16<1><<<dim3(48,4),256,0,stream>>>(dtin_bf, DTRR, dt_proj + (size_t)l*DINN*DTRR,
                                              dt_b + l*DINN, dtb, DINN, ROWS, DINN, DTRR, DTRR);
    scan_kernel<<<dim3(DINN/64, BATCH),64,0,stream>>>(dtb, dblb, xsc, xrb,
                     A_log + (size_t)l*DINN*DSTT, D_param + l*DINN, y_bf);
    // out_proj: M=392 N=3072 K=6144, accumulate into residual xm
    gemm_bf16<2><<<dim3(24,4),256,0,stream>>>(y_bf, DINN, out_proj + (size_t)l*DIMM*DINN,
                                              nullptr, xm, DIMM, ROWS, DIMM, DINN, DINN);
  }

  // ---- final proj + LN + mean ----
  cvt_bf16_kernel<<<(ROWS*DIMM+255)/256,256,0,stream>>>(xm, xm_bf, ROWS*DIMM);
  gemm_bf16<0><<<dim3(6,4),256,0,stream>>>(xm_bf, DIMM, proj_w, proj_b, xp, EMBEDD,
                                           ROWS, EMBEDD, DIMM, DIMM);
  ln_kernel<0><<<ROWS,256,0,stream>>>(xp, norm_w, norm_b, xp, EMBEDD);
  mean_kernel<<<(BATCH*EMBEDD+255)/256,256,0,stream>>>(xp, (float*)d_out);
}